// Round 3
// baseline (55.691 us; speedup 1.0000x reference)
//
#include <hip/hip_runtime.h>

// SlidingPosBiases3D: out[(h,w,d),(h',w',d')] = biases[h'-h+R, w'-w+R, d'-d+R]
// if all relative offsets lie in [0, 2R], else 0.  H=W=D=20, R=7 fixed by setup.
//
// 4 consecutive rows per block (same h,w; d = dbase..dbase+3 since 4 | 20):
//  - whole grid (2000 blocks x 256 thr) co-resident -> LDS staging happens once
//  - per column-chunk, the 4x4 needed bias values depend only on (k - r):
//    7 LDS loads feed 4 float4 stores.

typedef float v4f __attribute__((ext_vector_type(4)));  // native vec for nontemporal builtin

constexpr int R  = 7;
constexpr int S1 = 2 * R + 1;      // 15
constexpr int SB = S1 * S1 * S1;   // 3375 floats = 13.5 KB

constexpr int H = 20, W = 20, D = 20;
constexpr int N = H * W * D;       // 8000
constexpr int NV = N / 4;          // 2000 float4 per row
constexpr int RPB = 4;             // rows per block (divides D)
constexpr int NBLK = N / RPB;      // 2000 blocks

__global__ __launch_bounds__(256)
void SlidingPosBiases3D_kernel(const float* __restrict__ biases,
                               float* __restrict__ out) {
    __shared__ float sb[SB];
    for (int i = threadIdx.x; i < SB; i += 256)
        sb[i] = biases[i];
    __syncthreads();

    const int row0  = blockIdx.x * RPB;
    const int dbase = row0 % D;            // rows have d = dbase + r, r<4
    const int hw    = row0 / D;            // uniform across the 4 rows
    const int w     = hw % W;
    const int h     = hw / W;

    float* __restrict__ obase = out + (size_t)row0 * N;

    for (int v = threadIdx.x; v < NV; v += 256) {
        const int col = v * 4;
        const int d0  = col % D;           // 0,4,...,16 (4 | D)
        const int rem = col / D;
        const int wp  = rem % W;
        const int hp  = rem / W;

        const int ih = hp - h + R;
        const int iw = wp - w + R;
        const bool ok = ((unsigned)ih < (unsigned)S1) & ((unsigned)iw < (unsigned)S1);
        const int base = ih * (S1 * S1) + iw * S1;
        const int e    = d0 - dbase + R;   // id for (row r, elem k) = e + k - r

        float t[7];                        // t[j] = bias at id = e-3+j (masked)
        #pragma unroll
        for (int j = 0; j < 7; ++j) {
            const int id = e - 3 + j;
            const bool m = ok & ((unsigned)id < (unsigned)S1);
            int idc = id < 0 ? 0 : (id > S1 - 1 ? S1 - 1 : id);
            const int addr = ok ? base + idc : 0;   // always in-bounds
            t[j] = m ? sb[addr] : 0.f;
        }

        #pragma unroll
        for (int r = 0; r < RPB; ++r) {
            v4f val = { t[3 - r], t[4 - r], t[5 - r], t[6 - r] };
            __builtin_nontemporal_store(val, (v4f*)(obase + (size_t)r * N) + v);
        }
    }
}

extern "C" void kernel_launch(void* const* d_in, const int* in_sizes, int n_in,
                              void* d_out, int out_size, void* d_ws, size_t ws_size,
                              hipStream_t stream) {
    const float* biases = (const float*)d_in[0];
    float* out = (float*)d_out;
    SlidingPosBiases3D_kernel<<<NBLK, 256, 0, stream>>>(biases, out);
}

// Round 4
// 41.919 us; speedup vs baseline: 1.3285x; 1.3285x over previous
//
#include <hip/hip_runtime.h>

// SlidingPosBiases3D: out[(h,w,d),(h',w',d')] = biases[h'-h+R, w'-w+R, d'-d+R]
// if all relative offsets lie in [0, 2R], else 0.  H=W=D=20, R=7 fixed by setup.
//
// 4 consecutive rows per block (same h,w; d = dbase..dbase+3 since 4 | 20):
//  - whole grid (2000 blocks x 256 thr) co-resident -> LDS staging happens once
//  - per column-chunk, the 4x4 needed bias values depend only on (k - r):
//    7 LDS loads feed 4 float4 stores.
// R3 A/B: plain stores (nontemporal cost ~17% BW — bypassed L2 write aggregation).

constexpr int R  = 7;
constexpr int S1 = 2 * R + 1;      // 15
constexpr int SB = S1 * S1 * S1;   // 3375 floats = 13.5 KB

constexpr int H = 20, W = 20, D = 20;
constexpr int N = H * W * D;       // 8000
constexpr int NV = N / 4;          // 2000 float4 per row
constexpr int RPB = 4;             // rows per block (divides D)
constexpr int NBLK = N / RPB;      // 2000 blocks

__global__ __launch_bounds__(256)
void SlidingPosBiases3D_kernel(const float* __restrict__ biases,
                               float* __restrict__ out) {
    __shared__ float sb[SB];
    for (int i = threadIdx.x; i < SB; i += 256)
        sb[i] = biases[i];
    __syncthreads();

    const int row0  = blockIdx.x * RPB;
    const int dbase = row0 % D;            // rows have d = dbase + r, r<4
    const int hw    = row0 / D;            // uniform across the 4 rows
    const int w     = hw % W;
    const int h     = hw / W;

    float* __restrict__ obase = out + (size_t)row0 * N;

    for (int v = threadIdx.x; v < NV; v += 256) {
        const int col = v * 4;
        const int d0  = col % D;           // 0,4,...,16 (4 | D)
        const int rem = col / D;
        const int wp  = rem % W;
        const int hp  = rem / W;

        const int ih = hp - h + R;
        const int iw = wp - w + R;
        const bool ok = ((unsigned)ih < (unsigned)S1) & ((unsigned)iw < (unsigned)S1);
        const int base = ih * (S1 * S1) + iw * S1;
        const int e    = d0 - dbase + R;   // id for (row r, elem k) = e + k - r

        float t[7];                        // t[j] = bias at id = e-3+j (masked)
        #pragma unroll
        for (int j = 0; j < 7; ++j) {
            const int id = e - 3 + j;
            const bool m = ok & ((unsigned)id < (unsigned)S1);
            int idc = id < 0 ? 0 : (id > S1 - 1 ? S1 - 1 : id);
            const int addr = ok ? base + idc : 0;   // always in-bounds
            t[j] = m ? sb[addr] : 0.f;
        }

        #pragma unroll
        for (int r = 0; r < RPB; ++r) {
            float4 val = make_float4(t[3 - r], t[4 - r], t[5 - r], t[6 - r]);
            *((float4*)(obase + (size_t)r * N) + v) = val;
        }
    }
}

extern "C" void kernel_launch(void* const* d_in, const int* in_sizes, int n_in,
                              void* d_out, int out_size, void* d_ws, size_t ws_size,
                              hipStream_t stream) {
    const float* biases = (const float*)d_in[0];
    float* out = (float*)d_out;
    SlidingPosBiases3D_kernel<<<NBLK, 256, 0, stream>>>(biases, out);
}

// Round 5
// 40.161 us; speedup vs baseline: 1.3867x; 1.0438x over previous
//
#include <hip/hip_runtime.h>

// SlidingPosBiases3D: out[(h,w,d),(h',w',d')] = biases[h'-h+R, w'-w+R, d'-d+R]
// if all relative offsets lie in [0, 2R], else 0.  H=W=D=20, R=7 fixed by setup.
//
// Work item = (row-group g, vec-column v): 4 consecutive rows (same h,w;
// d = 4g%20 .. +3) x one float4 column chunk. 7 LDS loads feed 4 float4
// stores (value depends only on k - r). Flat grid-stride over 4M items with
// 2048 blocks (exactly 8/CU) gives perfect per-CU balance.
// Plain stores (R3: nontemporal cost ~17% BW). Staging vectorized as float4.

constexpr int R  = 7;
constexpr int S1 = 2 * R + 1;      // 15
constexpr int SB = S1 * S1 * S1;   // 3375 floats = 13.5 KB

constexpr int H = 20, W = 20, D = 20;
constexpr int N = H * W * D;       // 8000
constexpr int NV = N / 4;          // 2000 float4 per row
constexpr int RPB = 4;             // rows per group (divides D)
constexpr int NGRP = N / RPB;      // 2000 row-groups
constexpr long long NITEMS = (long long)NGRP * NV;   // 4,000,000
constexpr int NBLK = 2048;         // 8 blocks/CU exactly
constexpr int NTHR = 256;

__global__ __launch_bounds__(NTHR)
void SlidingPosBiases3D_kernel(const float* __restrict__ biases,
                               float* __restrict__ out) {
    __shared__ __align__(16) float sb[SB + 1];
    {
        const float4* b4 = (const float4*)biases;
        float4* s4 = (float4*)sb;
        for (int i = threadIdx.x; i < SB / 4; i += NTHR)   // 843 vec4 = floats 0..3371
            s4[i] = b4[i];
        if (threadIdx.x < 3)
            sb[3372 + threadIdx.x] = biases[3372 + threadIdx.x];
    }
    __syncthreads();

    for (int idx = blockIdx.x * NTHR + threadIdx.x; idx < (int)NITEMS;
         idx += NBLK * NTHR) {
        const int g = idx / NV;            // row-group (magic div)
        const int v = idx - g * NV;        // vec column

        const int row0  = g * RPB;
        const int dbase = row0 % D;        // rows have d = dbase + r, r<4
        const int hw    = row0 / D;
        const int w     = hw % W;
        const int h     = hw / W;

        const int col = v * 4;
        const int d0  = col % D;           // 0,4,...,16 (4 | D)
        const int rem = col / D;
        const int wp  = rem % W;
        const int hp  = rem / W;

        const int ih = hp - h + R;
        const int iw = wp - w + R;
        const bool ok = ((unsigned)ih < (unsigned)S1) & ((unsigned)iw < (unsigned)S1);
        const int base = ih * (S1 * S1) + iw * S1;
        const int e    = d0 - dbase + R;   // id for (row r, elem k) = e + k - r

        float t[7];                        // t[j] = bias at id = e-3+j (masked)
        #pragma unroll
        for (int j = 0; j < 7; ++j) {
            const int id = e - 3 + j;
            const bool m = ok & ((unsigned)id < (unsigned)S1);
            int idc = id < 0 ? 0 : (id > S1 - 1 ? S1 - 1 : id);
            const int addr = ok ? base + idc : 0;   // always in-bounds
            t[j] = m ? sb[addr] : 0.f;
        }

        float* __restrict__ obase = out + (size_t)row0 * N;
        #pragma unroll
        for (int r = 0; r < RPB; ++r) {
            float4 val = make_float4(t[3 - r], t[4 - r], t[5 - r], t[6 - r]);
            *((float4*)(obase + (size_t)r * N) + v) = val;
        }
    }
}

extern "C" void kernel_launch(void* const* d_in, const int* in_sizes, int n_in,
                              void* d_out, int out_size, void* d_ws, size_t ws_size,
                              hipStream_t stream) {
    const float* biases = (const float*)d_in[0];
    float* out = (float*)d_out;
    SlidingPosBiases3D_kernel<<<NBLK, NTHR, 0, stream>>>(biases, out);
}

// Round 6
// 39.442 us; speedup vs baseline: 1.4120x; 1.0182x over previous
//
#include <hip/hip_runtime.h>

// SlidingPosBiases3D: out[(h,w,d),(h',w',d')] = biases[h'-h+R, w'-w+R, d'-d+R]
// if all relative offsets lie in [0, 2R], else 0.  H=W=D=20, R=7 fixed by setup.
//
// Work item = (row-group g, vec-column v): 4 consecutive rows (same h,w;
// d = 4g%20 .. +3) x one float4 column chunk. 7 bias loads feed 4 float4
// stores (value depends only on k - r). Flat grid-stride over 4M items with
// 2048 blocks (exactly 8/CU) gives perfect per-CU balance.
// R5: bias table (13.5 KB) read directly through L1 — no LDS staging, no
// __syncthreads preamble. Plain stores (R3: nontemporal cost ~17% BW).

constexpr int R  = 7;
constexpr int S1 = 2 * R + 1;      // 15
constexpr int SB = S1 * S1 * S1;   // 3375 floats = 13.5 KB

constexpr int H = 20, W = 20, D = 20;
constexpr int N = H * W * D;       // 8000
constexpr int NV = N / 4;          // 2000 float4 per row
constexpr int RPB = 4;             // rows per group (divides D)
constexpr int NGRP = N / RPB;      // 2000 row-groups
constexpr long long NITEMS = (long long)NGRP * NV;   // 4,000,000
constexpr int NBLK = 2048;         // 8 blocks/CU exactly
constexpr int NTHR = 256;

__global__ __launch_bounds__(NTHR)
void SlidingPosBiases3D_kernel(const float* __restrict__ biases,
                               float* __restrict__ out) {
    for (int idx = blockIdx.x * NTHR + threadIdx.x; idx < (int)NITEMS;
         idx += NBLK * NTHR) {
        const int g = idx / NV;            // row-group (magic div)
        const int v = idx - g * NV;        // vec column

        const int row0  = g * RPB;
        const int dbase = row0 % D;        // rows have d = dbase + r, r<4
        const int hw    = row0 / D;
        const int w     = hw % W;
        const int h     = hw / W;

        const int col = v * 4;
        const int d0  = col % D;           // 0,4,...,16 (4 | D)
        const int rem = col / D;
        const int wp  = rem % W;
        const int hp  = rem / W;

        const int ih = hp - h + R;
        const int iw = wp - w + R;
        const bool ok = ((unsigned)ih < (unsigned)S1) & ((unsigned)iw < (unsigned)S1);
        const int base = ih * (S1 * S1) + iw * S1;
        const int e    = d0 - dbase + R;   // id for (row r, elem k) = e + k - r

        float t[7];                        // t[j] = bias at id = e-3+j (masked)
        #pragma unroll
        for (int j = 0; j < 7; ++j) {
            const int id = e - 3 + j;
            const bool m = ok & ((unsigned)id < (unsigned)S1);
            int idc = id < 0 ? 0 : (id > S1 - 1 ? S1 - 1 : id);
            const int addr = ok ? base + idc : 0;   // always in-bounds
            t[j] = m ? biases[addr] : 0.f; // L1-resident (13.5 KB table)
        }

        float* __restrict__ obase = out + (size_t)row0 * N;
        #pragma unroll
        for (int r = 0; r < RPB; ++r) {
            float4 val = make_float4(t[3 - r], t[4 - r], t[5 - r], t[6 - r]);
            *((float4*)(obase + (size_t)r * N) + v) = val;
        }
    }
}

extern "C" void kernel_launch(void* const* d_in, const int* in_sizes, int n_in,
                              void* d_out, int out_size, void* d_ws, size_t ws_size,
                              hipStream_t stream) {
    const float* biases = (const float*)d_in[0];
    float* out = (float*)d_out;
    SlidingPosBiases3D_kernel<<<NBLK, NTHR, 0, stream>>>(biases, out);
}